// Round 12
// baseline (286.451 us; speedup 1.0000x reference)
//
#include <hip/hip_runtime.h>

#define N_NODES 131072
#define NE      2097152
#define CIN     64
#define HID     64
#define H2X     128   // 2*HID
#define NODESG  128   // nodes per graph
#define NGRAPH  1024
#define NCLS    4

#define NBUCK   256   // buckets = dst>>9
#define NPB     512   // nodes per bucket
#define HBLK    1024  // histogram blocks
#define EPB     2048  // edges per histogram/scatter block
#define DEGSC   1048576.0f   // 2^20 fixed-point for LDS deg accumulation
#define DEGMASK ((1ull << 40) - 1)

typedef short bf16x8 __attribute__((ext_vector_type(8)));
typedef float f32x4  __attribute__((ext_vector_type(4)));

// bf16 helpers (RNE; inputs finite)
__device__ __forceinline__ unsigned short f2b(float f) {
    unsigned int u = __float_as_uint(f);
    return (unsigned short)((u + 0x7fffu + ((u >> 16) & 1u)) >> 16);
}
__device__ __forceinline__ unsigned int pack2(float a, float b) {
    return (unsigned int)f2b(a) | ((unsigned int)f2b(b) << 16);
}
__device__ __forceinline__ float blo(unsigned u) { return __uint_as_float(u << 16); }
__device__ __forceinline__ float bhi(unsigned u) { return __uint_as_float(u & 0xffff0000u); }

// ---------------- W1/W2 -> global MFMA B-frag tables (once) ----------------

__global__ __launch_bounds__(256) void k_wswiz(
        const float* __restrict__ W1, const float* __restrict__ W2,
        unsigned short* __restrict__ wf1, unsigned short* __restrict__ wf2) {
    int tid = threadIdx.x;
    #pragma unroll
    for (int it = 0; it < 4; ++it) {
        int idx = tid + 256 * it;                 // W1: 16 frags (kt<2, nt<8) x 64 lanes
        int kt = idx >> 9, nt = (idx >> 6) & 7, l = idx & 63;
        int lm = l & 15, lq = l >> 4;
        unsigned pk[4];
        #pragma unroll
        for (int jp = 0; jp < 4; ++jp) {
            float w0 = W1[(kt*32 + lq*8 + 2*jp)     * H2X + nt*16 + lm];
            float w1 = W1[(kt*32 + lq*8 + 2*jp + 1) * H2X + nt*16 + lm];
            pk[jp] = pack2(w0, w1);
        }
        *(uint4*)&wf1[idx * 8] = make_uint4(pk[0], pk[1], pk[2], pk[3]);
    }
    #pragma unroll
    for (int it = 0; it < 4; ++it) {
        int idx = tid + 256 * it;                 // W2: 16 frags (kt<4, nt<4) x 64 lanes
        int kt = idx >> 8, nt = (idx >> 6) & 3, l = idx & 63;
        int lm = l & 15, lq = l >> 4;
        unsigned pk[4];
        #pragma unroll
        for (int jp = 0; jp < 4; ++jp) {
            float w0 = W2[(kt*32 + lq*8 + 2*jp)     * HID + nt*16 + lm];
            float w1 = W2[(kt*32 + lq*8 + 2*jp + 1) * HID + nt*16 + lm];
            pk[jp] = pack2(w0, w1);
        }
        *(uint4*)&wf2[idx * 8] = make_uint4(pk[0], pk[1], pk[2], pk[3]);
    }
}

// ---------------- bucketed counting sort (no global atomics) ----------------

__global__ __launch_bounds__(256) void k_hist(const int* __restrict__ dst,
                                              int* __restrict__ hist) {
    __shared__ unsigned bh[NBUCK];
    int t = threadIdx.x;
    bh[t] = 0;
    __syncthreads();
    int base = blockIdx.x * EPB;
    #pragma unroll
    for (int k = 0; k < EPB / 256; ++k) {
        int d = dst[base + t + 256 * k];
        atomicAdd(&bh[d >> 9], 1u);
    }
    __syncthreads();
    hist[t * HBLK + blockIdx.x] = (int)bh[t];   // bucket-major layout
}

__global__ void k_scan1(const int* __restrict__ in, int* __restrict__ out,
                        int* __restrict__ partial) {
    __shared__ int sd[256];
    int t = threadIdx.x;
    int base = blockIdx.x * 512;
    int c0 = in[base + 2*t];
    int c1 = in[base + 2*t + 1];
    int loc = c0 + c1;
    sd[t] = loc;
    __syncthreads();
    for (int off = 1; off < 256; off <<= 1) {
        int v = (t >= off) ? sd[t - off] : 0;
        __syncthreads();
        sd[t] += v;
        __syncthreads();
    }
    int excl = sd[t] - loc;
    out[base + 2*t]     = excl;
    out[base + 2*t + 1] = excl + c0;
    if (t == 255) partial[blockIdx.x] = sd[t];
}

__global__ void k_scan2(int* __restrict__ partial) {
    __shared__ int sd[256];
    int t = threadIdx.x;
    int p0 = partial[2*t], p1 = partial[2*t + 1];
    int loc = p0 + p1;
    sd[t] = loc;
    __syncthreads();
    for (int off = 1; off < 256; off <<= 1) {
        int v = (t >= off) ? sd[t - off] : 0;
        __syncthreads();
        sd[t] += v;
        __syncthreads();
    }
    int excl = sd[t] - loc;
    partial[2*t]     = excl;
    partial[2*t + 1] = excl + p0;
}

// scatter edges into bucket-major order; global base = hist(local scan) + partial
__global__ __launch_bounds__(256) void k_scatter(
        const int* __restrict__ src, const int* __restrict__ dst,
        const float* __restrict__ ew, const int* __restrict__ hist,
        const int* __restrict__ partial, unsigned long long* __restrict__ part) {
    __shared__ unsigned lcur[NBUCK];
    int t = threadIdx.x;
    int gi = t * HBLK + blockIdx.x;
    lcur[t] = (unsigned)(hist[gi] + partial[gi >> 9]);
    __syncthreads();
    int base = blockIdx.x * EPB;
    #pragma unroll
    for (int k = 0; k < EPB / 256; ++k) {
        int e = base + t + 256 * k;
        int s = src[e], d = dst[e];
        unsigned w = __float_as_uint(ew[e]);
        unsigned p = atomicAdd(&lcur[d >> 9], 1u);
        part[p] = ((unsigned long long)w << 32) |
                  ((unsigned long long)(unsigned)(d & 511) << 17) |
                  (unsigned long long)(unsigned)s;
    }
}

// one block per bucket: LDS u64 count+deg, LDS scan -> rowptr, LDS-rank CSR scatter
__global__ __launch_bounds__(256) void k_bucket(
        const unsigned long long* __restrict__ part, const int* __restrict__ hist,
        const int* __restrict__ partial, int2* __restrict__ csr,
        int* __restrict__ rowptr, int* __restrict__ counts, float* __restrict__ dis) {
    __shared__ unsigned long long dc[NPB];   // count<<40 | deg-fixed-point
    __shared__ unsigned cnt2[NPB];
    __shared__ int rp[NPB];
    __shared__ int sd[256];
    int t = threadIdx.x, b = blockIdx.x;
    dc[t] = 0; dc[t + 256] = 0;
    cnt2[t] = 0; cnt2[t + 256] = 0;
    __syncthreads();
    int start = hist[b * HBLK] + partial[2 * b];
    int end   = (b == NBUCK - 1) ? NE : (hist[(b + 1) * HBLK] + partial[2 * (b + 1)]);

    for (int j = start + t; j < end; j += 256) {
        unsigned long long p = part[j];
        unsigned dl = (unsigned)(p >> 17) & 511u;
        float w = __uint_as_float((unsigned)(p >> 32));
        atomicAdd(&dc[dl], (1ull << 40) | (unsigned long long)(unsigned)(w * DEGSC));
    }
    __syncthreads();

    unsigned long long d0 = dc[2*t], d1 = dc[2*t + 1];
    int c0 = (int)(d0 >> 40), c1 = (int)(d1 >> 40);
    int loc = c0 + c1;
    sd[t] = loc;
    __syncthreads();
    for (int off = 1; off < 256; off <<= 1) {
        int v = (t >= off) ? sd[t - off] : 0;
        __syncthreads();
        sd[t] += v;
        __syncthreads();
    }
    int excl = sd[t] - loc;
    rp[2*t] = excl; rp[2*t + 1] = excl + c0;

    int n0 = b * NPB;
    rowptr[n0 + 2*t]     = start + excl;
    rowptr[n0 + 2*t + 1] = start + excl + c0;
    counts[n0 + 2*t]     = c0;
    counts[n0 + 2*t + 1] = c1;
    float dg0 = (float)(d0 & DEGMASK) * (1.0f / DEGSC);
    float dg1 = (float)(d1 & DEGMASK) * (1.0f / DEGSC);
    dis[n0 + 2*t]     = rsqrtf(dg0 + 1.0f);
    dis[n0 + 2*t + 1] = rsqrtf(dg1 + 1.0f);
    __syncthreads();

    for (int j = start + t; j < end; j += 256) {
        unsigned long long p = part[j];
        unsigned dl = (unsigned)(p >> 17) & 511u;
        int s = (int)(p & 0x1ffffu);
        unsigned r = atomicAdd(&cnt2[dl], 1u);
        csr[start + rp[dl] + (int)r] = make_int2(s, (int)(unsigned)(p >> 32)); // raw ew
    }
}

// y = bf16( dis[node] * x )  (prescaled gather table)
__global__ void k_xcast(const float* __restrict__ x, const float* __restrict__ dis,
                        uint2* __restrict__ xb2) {
    int i = blockIdx.x * blockDim.x + threadIdx.x;   // over N*CIN/4
    float d = dis[i >> 4];
    float4 v = ((const float4*)x)[i];
    xb2[i] = make_uint2(pack2(d * v.x, d * v.y), pack2(d * v.z, d * v.w));
}

// ---- shared gather-pair macro body: quarter-wave (16 lanes/edge, 4 ch/lane) ----

#define GATHER_PAIR(TAB, pA, pB, nA, nB, cmA, cmB, a0,a1,a2,a3, b0,b1,b2,b3, vSA, vSB) \
    {                                                                                  \
        int   sA0 = __shfl(pA.x, qid),      sA1 = __shfl(pA.x, qid + 4);               \
        int   sA2 = __shfl(pA.x, qid + 8),  sA3 = __shfl(pA.x, qid + 12);              \
        float fA0 = __int_as_float(__shfl(pA.y, qid));                                 \
        float fA1 = __int_as_float(__shfl(pA.y, qid + 4));                             \
        float fA2 = __int_as_float(__shfl(pA.y, qid + 8));                             \
        float fA3 = __int_as_float(__shfl(pA.y, qid + 12));                            \
        int   sB0 = __shfl(pB.x, qid),      sB1 = __shfl(pB.x, qid + 4);               \
        int   sB2 = __shfl(pB.x, qid + 8),  sB3 = __shfl(pB.x, qid + 12);              \
        float fB0 = __int_as_float(__shfl(pB.y, qid));                                 \
        float fB1 = __int_as_float(__shfl(pB.y, qid + 4));                             \
        float fB2 = __int_as_float(__shfl(pB.y, qid + 8));                             \
        float fB3 = __int_as_float(__shfl(pB.y, qid + 12));                            \
        uint2 vA0 = TAB[((unsigned)sA0 << 4) | ql];                                    \
        uint2 vA1 = TAB[((unsigned)sA1 << 4) | ql];                                    \
        uint2 vA2 = TAB[((unsigned)sA2 << 4) | ql];                                    \
        uint2 vA3 = TAB[((unsigned)sA3 << 4) | ql];                                    \
        uint2 vB0 = TAB[((unsigned)sB0 << 4) | ql];                                    \
        uint2 vB1 = TAB[((unsigned)sB1 << 4) | ql];                                    \
        uint2 vB2 = TAB[((unsigned)sB2 << 4) | ql];                                    \
        uint2 vB3 = TAB[((unsigned)sB3 << 4) | ql];                                    \
        vSA = TAB[((unsigned)nA << 4) | ql];                                           \
        vSB = TAB[((unsigned)nB << 4) | ql];                                           \
        a0 = fmaf(fA0, blo(vA0.x), a0); a1 = fmaf(fA0, bhi(vA0.x), a1);                \
        a2 = fmaf(fA0, blo(vA0.y), a2); a3 = fmaf(fA0, bhi(vA0.y), a3);                \
        a0 = fmaf(fA1, blo(vA1.x), a0); a1 = fmaf(fA1, bhi(vA1.x), a1);                \
        a2 = fmaf(fA1, blo(vA1.y), a2); a3 = fmaf(fA1, bhi(vA1.y), a3);                \
        a0 = fmaf(fA2, blo(vA2.x), a0); a1 = fmaf(fA2, bhi(vA2.x), a1);                \
        a2 = fmaf(fA2, blo(vA2.y), a2); a3 = fmaf(fA2, bhi(vA2.y), a3);                \
        a0 = fmaf(fA3, blo(vA3.x), a0); a1 = fmaf(fA3, bhi(vA3.x), a1);                \
        a2 = fmaf(fA3, blo(vA3.y), a2); a3 = fmaf(fA3, bhi(vA3.y), a3);                \
        b0 = fmaf(fB0, blo(vB0.x), b0); b1 = fmaf(fB0, bhi(vB0.x), b1);                \
        b2 = fmaf(fB0, blo(vB0.y), b2); b3 = fmaf(fB0, bhi(vB0.y), b3);                \
        b0 = fmaf(fB1, blo(vB1.x), b0); b1 = fmaf(fB1, bhi(vB1.x), b1);                \
        b2 = fmaf(fB1, blo(vB1.y), b2); b3 = fmaf(fB1, bhi(vB1.y), b3);                \
        b0 = fmaf(fB2, blo(vB2.x), b0); b1 = fmaf(fB2, bhi(vB2.x), b1);                \
        b2 = fmaf(fB2, blo(vB2.y), b2); b3 = fmaf(fB2, bhi(vB2.y), b3);                \
        b0 = fmaf(fB3, blo(vB3.x), b0); b1 = fmaf(fB3, bhi(vB3.x), b1);                \
        b2 = fmaf(fB3, blo(vB3.y), b2); b3 = fmaf(fB3, bhi(vB3.y), b3);                \
        int tsA = (cmA > 16) ? ((cmA - 13) >> 2) : 0;                                  \
        for (int k = 0; k < tsA; ++k) {                                                \
            int jj = 16 + 4 * k + qid;                                                 \
            int   s = __shfl(pA.x, jj);                                                \
            float f = __int_as_float(__shfl(pA.y, jj));                                \
            uint2 v = TAB[((unsigned)s << 4) | ql];                                    \
            a0 = fmaf(f, blo(v.x), a0); a1 = fmaf(f, bhi(v.x), a1);                    \
            a2 = fmaf(f, blo(v.y), a2); a3 = fmaf(f, bhi(v.y), a3);                    \
        }                                                                              \
        int tsB = (cmB > 16) ? ((cmB - 13) >> 2) : 0;                                  \
        for (int k = 0; k < tsB; ++k) {                                                \
            int jj = 16 + 4 * k + qid;                                                 \
            int   s = __shfl(pB.x, jj);                                                \
            float f = __int_as_float(__shfl(pB.y, jj));                                \
            uint2 v = TAB[((unsigned)s << 4) | ql];                                    \
            b0 = fmaf(f, blo(v.x), b0); b1 = fmaf(f, bhi(v.x), b1);                    \
            b2 = fmaf(f, blo(v.y), b2); b3 = fmaf(f, bhi(v.y), b3);                    \
        }                                                                              \
        a0 += __shfl_xor(a0, 16); a1 += __shfl_xor(a1, 16);                            \
        a2 += __shfl_xor(a2, 16); a3 += __shfl_xor(a3, 16);                            \
        a0 += __shfl_xor(a0, 32); a1 += __shfl_xor(a1, 32);                            \
        a2 += __shfl_xor(a2, 32); a3 += __shfl_xor(a3, 32);                            \
        b0 += __shfl_xor(b0, 16); b1 += __shfl_xor(b1, 16);                            \
        b2 += __shfl_xor(b2, 16); b3 += __shfl_xor(b3, 16);                            \
        b0 += __shfl_xor(b0, 32); b1 += __shfl_xor(b1, 32);                            \
        b2 += __shfl_xor(b2, 32); b3 += __shfl_xor(b3, 32);                            \
    }

// -------- fused layer 1+2-GEMM: t2u = bf16( dis * (relu((A_hat x)W1 + b1)) W2 ) ----
// bounds(256,4): empirically the only spill-free point for this kernel family
// (r6 bounds-6 / r9 bounds-8 both spilled).

__global__ __launch_bounds__(256, 4) void k_layer1(
        const uint2* __restrict__ xb2, const int2* __restrict__ csr,
        const int* __restrict__ rowptr, const int* __restrict__ counts,
        const float* __restrict__ dis, const unsigned short* __restrict__ wf1,
        const unsigned short* __restrict__ wf2, const float* __restrict__ b1,
        unsigned short* __restrict__ t2u) {
    __shared__ unsigned short sagg_b[32][72];     // bf16 agg tile, 144B rows
    __shared__ unsigned short sh1[32][136];       // bf16 h1 tile, 272B rows
    __shared__ float sb[H2X];
    int tid = threadIdx.x;
    if (tid < H2X) sb[tid] = b1[tid];

    int wave = tid >> 6, lane = tid & 63;
    int qid = lane >> 4, ql = lane & 15;
    int n0 = blockIdx.x * 32;
    int nb = n0 + wave * 8;

    int cm8[8], cnt8[8], rs8[8];
    float dn8[8];
    int2 myp[8];
    #pragma unroll
    for (int i = 0; i < 8; ++i) {
        rs8[i] = rowptr[nb + i];
        cnt8[i] = counts[nb + i];
        dn8[i] = dis[nb + i];
        cm8[i] = cnt8[i] < 64 ? cnt8[i] : 64;
    }
    #pragma unroll
    for (int i = 0; i < 8; ++i)
        myp[i] = (lane < cm8[i]) ? csr[rs8[i] + lane] : make_int2(0, 0);

    #pragma unroll
    for (int ip = 0; ip < 8; ip += 2) {
        int2 pA = myp[ip], pB = myp[ip + 1];
        int nA = nb + ip, nB = nA + 1;
        float a0 = 0.f, a1 = 0.f, a2 = 0.f, a3 = 0.f;
        float b0 = 0.f, b1v = 0.f, b2v = 0.f, b3 = 0.f;
        uint2 vSA, vSB;
        GATHER_PAIR(xb2, pA, pB, nA, nB, cm8[ip], cm8[ip + 1],
                    a0, a1, a2, a3, b0, b1v, b2v, b3, vSA, vSB);
        for (int jj = 64; jj < cnt8[ip]; ++jj) {   // degree >64: essentially never
            int2 p = csr[rs8[ip] + jj];
            float f = __int_as_float(p.y);
            uint2 v = xb2[((unsigned)p.x << 4) | ql];
            if (qid == 0) {
                a0 += f * blo(v.x); a1 += f * bhi(v.x);
                a2 += f * blo(v.y); a3 += f * bhi(v.y);
            }
        }
        for (int jj = 64; jj < cnt8[ip + 1]; ++jj) {
            int2 p = csr[rs8[ip + 1] + jj];
            float f = __int_as_float(p.y);
            uint2 v = xb2[((unsigned)p.x << 4) | ql];
            if (qid == 0) {
                b0 += f * blo(v.x); b1v += f * bhi(v.x);
                b2v += f * blo(v.y); b3 += f * bhi(v.y);
            }
        }
        if (qid == 0) {
            float dnA = dn8[ip], dnB = dn8[ip + 1];
            int m = wave * 8 + ip;
            *(uint2*)&sagg_b[m][ql * 4] =
                make_uint2(pack2(dnA * (a0 + blo(vSA.x)), dnA * (a1 + bhi(vSA.x))),
                           pack2(dnA * (a2 + blo(vSA.y)), dnA * (a3 + bhi(vSA.y))));
            *(uint2*)&sagg_b[m + 1][ql * 4] =
                make_uint2(pack2(dnB * (b0 + blo(vSB.x)), dnB * (b1v + bhi(vSB.x))),
                           pack2(dnB * (b2v + blo(vSB.y)), dnB * (b3 + bhi(vSB.y))));
        }
    }
    __syncthreads();

    // MFMA GEMM 1: agg(32x64) @ W1(64x128) -> relu+bias -> sh1 (bf16)
    int mt = wave & 1, ntb = (wave >> 1) * 4;
    int lm = lane & 15, lq = lane >> 4;
    bf16x8 af0 = *(const bf16x8*)&sagg_b[mt*16 + lm][lq * 8];
    bf16x8 af1 = *(const bf16x8*)&sagg_b[mt*16 + lm][32 + lq * 8];
    #pragma unroll
    for (int t = 0; t < 4; ++t) {
        int nt = ntb + t;
        bf16x8 bf0 = *(const bf16x8*)&wf1[(nt*64 + lane) * 8];
        bf16x8 bf1 = *(const bf16x8*)&wf1[((8 + nt)*64 + lane) * 8];
        f32x4 acc = {0.f, 0.f, 0.f, 0.f};
        acc = __builtin_amdgcn_mfma_f32_16x16x32_bf16(af0, bf0, acc, 0, 0, 0);
        acc = __builtin_amdgcn_mfma_f32_16x16x32_bf16(af1, bf1, acc, 0, 0, 0);
        int ch = nt*16 + lm;
        float bias = sb[ch];
        #pragma unroll
        for (int r = 0; r < 4; ++r)
            sh1[mt*16 + lq*4 + r][ch] = f2b(fmaxf(acc[r] + bias, 0.f));
    }
    __syncthreads();

    // MFMA GEMM 2: sh1(32x128) @ W2(128x64) -> t2u = bf16(dis * .)
    #pragma unroll
    for (int ti = 0; ti < 2; ++ti) {
        int t = wave * 2 + ti;                    // 8 tiles: 2 mt x 4 nt
        int mt2 = t & 1, nt2 = t >> 1;
        f32x4 acc = {0.f, 0.f, 0.f, 0.f};
        #pragma unroll
        for (int kt = 0; kt < 4; ++kt) {
            bf16x8 af = *(const bf16x8*)&sh1[mt2*16 + lm][kt*32 + lq*8];
            bf16x8 bf = *(const bf16x8*)&wf2[((kt*4 + nt2)*64 + lane) * 8];
            acc = __builtin_amdgcn_mfma_f32_16x16x32_bf16(af, bf, acc, 0, 0, 0);
        }
        int ch = nt2*16 + lm;
        #pragma unroll
        for (int r = 0; r < 4; ++r) {
            int node = n0 + mt2*16 + lq*4 + r;
            t2u[(size_t)node * HID + ch] = f2b(dis[node] * acc[r]);
        }
    }
}

// ---- layer 2 aggregation FUSED with FC: logits[g] += h2[n]·Wfc rows -------
// h2 = relu(dn*(sum ew*t2y + t2y[n]) + b2) dies in registers; each block's 32
// nodes belong to one graph (128/32=4 blocks/graph).

__global__ __launch_bounds__(256, 4) void k_agg2(
        const uint2* __restrict__ t2y, const int2* __restrict__ csr,
        const int* __restrict__ rowptr, const int* __restrict__ counts,
        const float* __restrict__ dis, const float* __restrict__ b2,
        const float* __restrict__ Wfc, float* __restrict__ logits) {
    int tid = threadIdx.x;
    int wave = tid >> 6, lane = tid & 63;
    int qid = lane >> 4, ql = lane & 15;
    float4 bb = *(const float4*)&b2[ql * 4];
    int n0 = blockIdx.x * 32;
    int nb = n0 + wave * 8;
    const float4* W4 = (const float4*)Wfc;

    int cm8[8], cnt8[8], rs8[8];
    float dn8[8];
    int2 myp[8];
    #pragma unroll
    for (int i = 0; i < 8; ++i) {
        rs8[i] = rowptr[nb + i];
        cnt8[i] = counts[nb + i];
        dn8[i] = dis[nb + i];
        cm8[i] = cnt8[i] < 64 ? cnt8[i] : 64;
    }
    #pragma unroll
    for (int i = 0; i < 8; ++i)
        myp[i] = (lane < cm8[i]) ? csr[rs8[i] + lane] : make_int2(0, 0);

    float4 lg = make_float4(0.f, 0.f, 0.f, 0.f);   // logit partial (valid on qid==0)

    #pragma unroll
    for (int ip = 0; ip < 8; ip += 2) {
        int2 pA = myp[ip], pB = myp[ip + 1];
        int nA = nb + ip, nB = nA + 1;
        float a0 = 0.f, a1 = 0.f, a2 = 0.f, a3 = 0.f;
        float b0 = 0.f, b1v = 0.f, b2v = 0.f, b3 = 0.f;
        uint2 vSA, vSB;
        GATHER_PAIR(t2y, pA, pB, nA, nB, cm8[ip], cm8[ip + 1],
                    a0, a1, a2, a3, b0, b1v, b2v, b3, vSA, vSB);
        for (int jj = 64; jj < cnt8[ip]; ++jj) {
            int2 p = csr[rs8[ip] + jj];
            float f = __int_as_float(p.y);
            uint2 v = t2y[((unsigned)p.x << 4) | ql];
            if (qid == 0) {
                a0 += f * blo(v.x); a1 += f * bhi(v.x);
                a2 += f * blo(v.y); a3 += f * bhi(v.y);
            }
        }
        for (int jj = 64; jj < cnt8[ip + 1]; ++jj) {
            int2 p = csr[rs8[ip + 1] + jj];
            float f = __int_as_float(p.y);
            uint2 v = t2y[((unsigned)p.x << 4) | ql];
            if (qid == 0) {
                b0 += f * blo(v.x); b1v += f * bhi(v.x);
                b2v += f * blo(v.y); b3 += f * bhi(v.y);
            }
        }
        if (qid == 0) {
            float dnA = dn8[ip], dnB = dn8[ip + 1];
            float oa0 = fmaxf(fmaf(dnA, a0 + blo(vSA.x), bb.x), 0.f);
            float oa1 = fmaxf(fmaf(dnA, a1 + bhi(vSA.x), bb.y), 0.f);
            float oa2 = fmaxf(fmaf(dnA, a2 + blo(vSA.y), bb.z), 0.f);
            float oa3 = fmaxf(fmaf(dnA, a3 + bhi(vSA.y), bb.w), 0.f);
            float ob0 = fmaxf(fmaf(dnB, b0 + blo(vSB.x), bb.x), 0.f);
            float ob1 = fmaxf(fmaf(dnB, b1v + bhi(vSB.x), bb.y), 0.f);
            float ob2 = fmaxf(fmaf(dnB, b2v + blo(vSB.y), bb.z), 0.f);
            float ob3 = fmaxf(fmaf(dnB, b3 + bhi(vSB.y), bb.w), 0.f);
            // FC: Wfc row index = (node_in_graph)*64 + ch, ch = 4*ql + r
            int baseA = (((unsigned)nA & 127u) << 6) + (ql << 2);
            int baseB = (((unsigned)nB & 127u) << 6) + (ql << 2);
            float4 w;
            w = W4[baseA + 0]; lg.x = fmaf(oa0, w.x, lg.x); lg.y = fmaf(oa0, w.y, lg.y);
                               lg.z = fmaf(oa0, w.z, lg.z); lg.w = fmaf(oa0, w.w, lg.w);
            w = W4[baseA + 1]; lg.x = fmaf(oa1, w.x, lg.x); lg.y = fmaf(oa1, w.y, lg.y);
                               lg.z = fmaf(oa1, w.z, lg.z); lg.w = fmaf(oa1, w.w, lg.w);
            w = W4[baseA + 2]; lg.x = fmaf(oa2, w.x, lg.x); lg.y = fmaf(oa2, w.y, lg.y);
                               lg.z = fmaf(oa2, w.z, lg.z); lg.w = fmaf(oa2, w.w, lg.w);
            w = W4[baseA + 3]; lg.x = fmaf(oa3, w.x, lg.x); lg.y = fmaf(oa3, w.y, lg.y);
                               lg.z = fmaf(oa3, w.z, lg.z); lg.w = fmaf(oa3, w.w, lg.w);
            w = W4[baseB + 0]; lg.x = fmaf(ob0, w.x, lg.x); lg.y = fmaf(ob0, w.y, lg.y);
                               lg.z = fmaf(ob0, w.z, lg.z); lg.w = fmaf(ob0, w.w, lg.w);
            w = W4[baseB + 1]; lg.x = fmaf(ob1, w.x, lg.x); lg.y = fmaf(ob1, w.y, lg.y);
                               lg.z = fmaf(ob1, w.z, lg.z); lg.w = fmaf(ob1, w.w, lg.w);
            w = W4[baseB + 2]; lg.x = fmaf(ob2, w.x, lg.x); lg.y = fmaf(ob2, w.y, lg.y);
                               lg.z = fmaf(ob2, w.z, lg.z); lg.w = fmaf(ob2, w.w, lg.w);
            w = W4[baseB + 3]; lg.x = fmaf(ob3, w.x, lg.x); lg.y = fmaf(ob3, w.y, lg.y);
                               lg.z = fmaf(ob3, w.z, lg.z); lg.w = fmaf(ob3, w.w, lg.w);
        }
    }
    // butterfly reduce (inactive lanes hold zeros)
    #pragma unroll
    for (int m = 1; m < 64; m <<= 1) {
        lg.x += __shfl_xor(lg.x, m); lg.y += __shfl_xor(lg.y, m);
        lg.z += __shfl_xor(lg.z, m); lg.w += __shfl_xor(lg.w, m);
    }
    if (lane == 0) {
        float* lgp = &logits[(n0 >> 7) * 4];
        atomicAdd(&lgp[0], lg.x); atomicAdd(&lgp[1], lg.y);
        atomicAdd(&lgp[2], lg.z); atomicAdd(&lgp[3], lg.w);
    }
}

// ---------------- bias + softmax ----------------

__global__ void k_soft(const float* __restrict__ logits, const float* __restrict__ bfc,
                       float* __restrict__ out) {
    int g = blockIdx.x * blockDim.x + threadIdx.x;
    if (g < NGRAPH) {
        float4 l = ((const float4*)logits)[g];
        float l0 = l.x + bfc[0], l1 = l.y + bfc[1];
        float l2 = l.z + bfc[2], l3 = l.w + bfc[3];
        float mx = fmaxf(fmaxf(l0, l1), fmaxf(l2, l3));
        float e0 = expf(l0 - mx), e1 = expf(l1 - mx);
        float e2 = expf(l2 - mx), e3 = expf(l3 - mx);
        float inv = 1.f / (e0 + e1 + e2 + e3);
        ((float4*)out)[g] = make_float4(e0 * inv, e1 * inv, e2 * inv, e3 * inv);
    }
}

// ---------------- launch ----------------

extern "C" void kernel_launch(void* const* d_in, const int* in_sizes, int n_in,
                              void* d_out, int out_size, void* d_ws, size_t ws_size,
                              hipStream_t stream) {
    const float* x   = (const float*)d_in[0];
    const int*   ei  = (const int*)  d_in[1];
    const float* ea  = (const float*)d_in[2];
    const float* W1  = (const float*)d_in[3];
    const float* b1  = (const float*)d_in[4];
    const float* W2  = (const float*)d_in[5];
    const float* b2  = (const float*)d_in[6];
    const float* Wfc = (const float*)d_in[7];
    const float* bfc = (const float*)d_in[8];
    float* out = (float*)d_out;
    const int* src = ei;
    const int* dst = ei + NE;

    char* ws = (char*)d_ws;
    size_t off = 0;
    int*   hist   = (int*)  (ws + off); off += (size_t)NBUCK * HBLK * 4;  // 1 MB
    int*   partial= (int*)  (ws + off); off += 4096;
    float* logits = (float*)(ws + off); off += (size_t)NGRAPH * 4 * 4;    // 16 KB
    int*   counts = (int*)  (ws + off); off += (size_t)N_NODES * 4;
    int*   rowptr = (int*)  (ws + off); off += (size_t)N_NODES * 4;
    float* dis    = (float*)(ws + off); off += (size_t)N_NODES * 4;
    unsigned short* wf1 = (unsigned short*)(ws + off); off += 8192 * 2;   // 16 KB
    unsigned short* wf2 = (unsigned short*)(ws + off); off += 8192 * 2;   // 16 KB
    int2*  csr    = (int2*) (ws + off); off += (size_t)NE * 8;
    uint2* xb2    = (uint2*)(ws + off); off += (size_t)N_NODES * CIN * 2;
    unsigned short* t2u = (unsigned short*)(ws + off); off += (size_t)N_NODES * HID * 2;
    unsigned long long* part = (unsigned long long*)t2u; // 16MB <= 16.7MB; dead before k_layer1

    // zero hist + partial + logits (contiguous)
    hipMemsetAsync(hist, 0, (size_t)NBUCK * HBLK * 4 + 4096 + (size_t)NGRAPH * 16, stream);

    k_wswiz  <<<1, 256, 0, stream>>>(W1, W2, wf1, wf2);
    k_hist   <<<HBLK, 256, 0, stream>>>(dst, hist);
    k_scan1  <<<NBUCK * HBLK / 512, 256, 0, stream>>>(hist, hist, partial);
    k_scan2  <<<1, 256, 0, stream>>>(partial);
    k_scatter<<<HBLK, 256, 0, stream>>>(src, dst, ea, hist, partial, part);
    k_bucket <<<NBUCK, 256, 0, stream>>>(part, hist, partial, csr, rowptr, counts, dis);
    k_xcast  <<<(N_NODES * CIN / 4) / 256, 256, 0, stream>>>(x, dis, xb2);
    k_layer1 <<<N_NODES / 32, 256, 0, stream>>>(xb2, csr, rowptr, counts, dis,
                                                wf1, wf2, b1, t2u);
    k_agg2   <<<N_NODES / 32, 256, 0, stream>>>((const uint2*)t2u, csr, rowptr,
                                                counts, dis, b2, Wfc, logits);
    k_soft   <<<(NGRAPH + 255) / 256, 256, 0, stream>>>(logits, bfc, out);
}

// Round 13
// 264.217 us; speedup vs baseline: 1.0842x; 1.0842x over previous
//
#include <hip/hip_runtime.h>

#define N_NODES 131072
#define NE      2097152
#define CIN     64
#define HID     64
#define H2X     128   // 2*HID
#define NODESG  128   // nodes per graph
#define NGRAPH  1024
#define NCLS    4

#define NBUCK   256   // buckets = dst>>9
#define NPB     512   // nodes per bucket
#define HBLK    1024  // histogram blocks
#define EPB     2048  // edges per histogram/scatter block
#define DEGSC   1048576.0f   // 2^20 fixed-point for LDS deg accumulation
#define DEGMASK ((1ull << 40) - 1)

typedef short bf16x8 __attribute__((ext_vector_type(8)));
typedef float f32x4  __attribute__((ext_vector_type(4)));

// bf16 helpers (RNE; inputs finite)
__device__ __forceinline__ unsigned short f2b(float f) {
    unsigned int u = __float_as_uint(f);
    return (unsigned short)((u + 0x7fffu + ((u >> 16) & 1u)) >> 16);
}
__device__ __forceinline__ unsigned int pack2(float a, float b) {
    return (unsigned int)f2b(a) | ((unsigned int)f2b(b) << 16);
}
__device__ __forceinline__ float blo(unsigned u) { return __uint_as_float(u << 16); }
__device__ __forceinline__ float bhi(unsigned u) { return __uint_as_float(u & 0xffff0000u); }

// ---------------- W1/W2 -> global MFMA B-frag tables (once) ----------------

__global__ __launch_bounds__(256) void k_wswiz(
        const float* __restrict__ W1, const float* __restrict__ W2,
        unsigned short* __restrict__ wf1, unsigned short* __restrict__ wf2) {
    int tid = threadIdx.x;
    #pragma unroll
    for (int it = 0; it < 4; ++it) {
        int idx = tid + 256 * it;                 // W1: 16 frags (kt<2, nt<8) x 64 lanes
        int kt = idx >> 9, nt = (idx >> 6) & 7, l = idx & 63;
        int lm = l & 15, lq = l >> 4;
        unsigned pk[4];
        #pragma unroll
        for (int jp = 0; jp < 4; ++jp) {
            float w0 = W1[(kt*32 + lq*8 + 2*jp)     * H2X + nt*16 + lm];
            float w1 = W1[(kt*32 + lq*8 + 2*jp + 1) * H2X + nt*16 + lm];
            pk[jp] = pack2(w0, w1);
        }
        *(uint4*)&wf1[idx * 8] = make_uint4(pk[0], pk[1], pk[2], pk[3]);
    }
    #pragma unroll
    for (int it = 0; it < 4; ++it) {
        int idx = tid + 256 * it;                 // W2: 16 frags (kt<4, nt<4) x 64 lanes
        int kt = idx >> 8, nt = (idx >> 6) & 3, l = idx & 63;
        int lm = l & 15, lq = l >> 4;
        unsigned pk[4];
        #pragma unroll
        for (int jp = 0; jp < 4; ++jp) {
            float w0 = W2[(kt*32 + lq*8 + 2*jp)     * HID + nt*16 + lm];
            float w1 = W2[(kt*32 + lq*8 + 2*jp + 1) * HID + nt*16 + lm];
            pk[jp] = pack2(w0, w1);
        }
        *(uint4*)&wf2[idx * 8] = make_uint4(pk[0], pk[1], pk[2], pk[3]);
    }
}

// ---------------- bucketed counting sort (no global atomics) ----------------

__global__ __launch_bounds__(256) void k_hist(const int* __restrict__ dst,
                                              int* __restrict__ hist) {
    __shared__ unsigned bh[NBUCK];
    int t = threadIdx.x;
    bh[t] = 0;
    __syncthreads();
    int base = blockIdx.x * EPB;
    #pragma unroll
    for (int k = 0; k < EPB / 256; ++k) {
        int d = dst[base + t + 256 * k];
        atomicAdd(&bh[d >> 9], 1u);
    }
    __syncthreads();
    hist[t * HBLK + blockIdx.x] = (int)bh[t];   // bucket-major layout
}

__global__ void k_scan1(const int* __restrict__ in, int* __restrict__ out,
                        int* __restrict__ partial) {
    __shared__ int sd[256];
    int t = threadIdx.x;
    int base = blockIdx.x * 512;
    int c0 = in[base + 2*t];
    int c1 = in[base + 2*t + 1];
    int loc = c0 + c1;
    sd[t] = loc;
    __syncthreads();
    for (int off = 1; off < 256; off <<= 1) {
        int v = (t >= off) ? sd[t - off] : 0;
        __syncthreads();
        sd[t] += v;
        __syncthreads();
    }
    int excl = sd[t] - loc;
    out[base + 2*t]     = excl;
    out[base + 2*t + 1] = excl + c0;
    if (t == 255) partial[blockIdx.x] = sd[t];
}

__global__ void k_scan2(int* __restrict__ partial) {
    __shared__ int sd[256];
    int t = threadIdx.x;
    int p0 = partial[2*t], p1 = partial[2*t + 1];
    int loc = p0 + p1;
    sd[t] = loc;
    __syncthreads();
    for (int off = 1; off < 256; off <<= 1) {
        int v = (t >= off) ? sd[t - off] : 0;
        __syncthreads();
        sd[t] += v;
        __syncthreads();
    }
    int excl = sd[t] - loc;
    partial[2*t]     = excl;
    partial[2*t + 1] = excl + p0;
}

// scatter edges into bucket-major order; global base = hist(local scan) + partial
__global__ __launch_bounds__(256) void k_scatter(
        const int* __restrict__ src, const int* __restrict__ dst,
        const float* __restrict__ ew, const int* __restrict__ hist,
        const int* __restrict__ partial, unsigned long long* __restrict__ part) {
    __shared__ unsigned lcur[NBUCK];
    int t = threadIdx.x;
    int gi = t * HBLK + blockIdx.x;
    lcur[t] = (unsigned)(hist[gi] + partial[gi >> 9]);
    __syncthreads();
    int base = blockIdx.x * EPB;
    #pragma unroll
    for (int k = 0; k < EPB / 256; ++k) {
        int e = base + t + 256 * k;
        int s = src[e], d = dst[e];
        unsigned w = __float_as_uint(ew[e]);
        unsigned p = atomicAdd(&lcur[d >> 9], 1u);
        part[p] = ((unsigned long long)w << 32) |
                  ((unsigned long long)(unsigned)(d & 511) << 17) |
                  (unsigned long long)(unsigned)s;
    }
}

// one block per bucket: LDS u64 count+deg, LDS scan -> rowptr, LDS-rank CSR scatter
__global__ __launch_bounds__(256) void k_bucket(
        const unsigned long long* __restrict__ part, const int* __restrict__ hist,
        const int* __restrict__ partial, int2* __restrict__ csr,
        int* __restrict__ rowptr, int* __restrict__ counts, float* __restrict__ dis) {
    __shared__ unsigned long long dc[NPB];   // count<<40 | deg-fixed-point
    __shared__ unsigned cnt2[NPB];
    __shared__ int rp[NPB];
    __shared__ int sd[256];
    int t = threadIdx.x, b = blockIdx.x;
    dc[t] = 0; dc[t + 256] = 0;
    cnt2[t] = 0; cnt2[t + 256] = 0;
    __syncthreads();
    int start = hist[b * HBLK] + partial[2 * b];
    int end   = (b == NBUCK - 1) ? NE : (hist[(b + 1) * HBLK] + partial[2 * (b + 1)]);

    for (int j = start + t; j < end; j += 256) {
        unsigned long long p = part[j];
        unsigned dl = (unsigned)(p >> 17) & 511u;
        float w = __uint_as_float((unsigned)(p >> 32));
        atomicAdd(&dc[dl], (1ull << 40) | (unsigned long long)(unsigned)(w * DEGSC));
    }
    __syncthreads();

    unsigned long long d0 = dc[2*t], d1 = dc[2*t + 1];
    int c0 = (int)(d0 >> 40), c1 = (int)(d1 >> 40);
    int loc = c0 + c1;
    sd[t] = loc;
    __syncthreads();
    for (int off = 1; off < 256; off <<= 1) {
        int v = (t >= off) ? sd[t - off] : 0;
        __syncthreads();
        sd[t] += v;
        __syncthreads();
    }
    int excl = sd[t] - loc;
    rp[2*t] = excl; rp[2*t + 1] = excl + c0;

    int n0 = b * NPB;
    rowptr[n0 + 2*t]     = start + excl;
    rowptr[n0 + 2*t + 1] = start + excl + c0;
    counts[n0 + 2*t]     = c0;
    counts[n0 + 2*t + 1] = c1;
    float dg0 = (float)(d0 & DEGMASK) * (1.0f / DEGSC);
    float dg1 = (float)(d1 & DEGMASK) * (1.0f / DEGSC);
    dis[n0 + 2*t]     = rsqrtf(dg0 + 1.0f);
    dis[n0 + 2*t + 1] = rsqrtf(dg1 + 1.0f);
    __syncthreads();

    for (int j = start + t; j < end; j += 256) {
        unsigned long long p = part[j];
        unsigned dl = (unsigned)(p >> 17) & 511u;
        int s = (int)(p & 0x1ffffu);
        unsigned r = atomicAdd(&cnt2[dl], 1u);
        csr[start + rp[dl] + (int)r] = make_int2(s, (int)(unsigned)(p >> 32)); // raw ew
    }
}

// y = bf16( dis[node] * x )  (prescaled gather table)
__global__ void k_xcast(const float* __restrict__ x, const float* __restrict__ dis,
                        uint2* __restrict__ xb2) {
    int i = blockIdx.x * blockDim.x + threadIdx.x;   // over N*CIN/4
    float d = dis[i >> 4];
    float4 v = ((const float4*)x)[i];
    xb2[i] = make_uint2(pack2(d * v.x, d * v.y), pack2(d * v.z, d * v.w));
}

// ---- shared gather-pair macro body: quarter-wave (16 lanes/edge, 4 ch/lane) ----

#define GATHER_PAIR(TAB, pA, pB, nA, nB, cmA, cmB, a0,a1,a2,a3, b0,b1,b2,b3, vSA, vSB) \
    {                                                                                  \
        int   sA0 = __shfl(pA.x, qid),      sA1 = __shfl(pA.x, qid + 4);               \
        int   sA2 = __shfl(pA.x, qid + 8),  sA3 = __shfl(pA.x, qid + 12);              \
        float fA0 = __int_as_float(__shfl(pA.y, qid));                                 \
        float fA1 = __int_as_float(__shfl(pA.y, qid + 4));                             \
        float fA2 = __int_as_float(__shfl(pA.y, qid + 8));                             \
        float fA3 = __int_as_float(__shfl(pA.y, qid + 12));                            \
        int   sB0 = __shfl(pB.x, qid),      sB1 = __shfl(pB.x, qid + 4);               \
        int   sB2 = __shfl(pB.x, qid + 8),  sB3 = __shfl(pB.x, qid + 12);              \
        float fB0 = __int_as_float(__shfl(pB.y, qid));                                 \
        float fB1 = __int_as_float(__shfl(pB.y, qid + 4));                             \
        float fB2 = __int_as_float(__shfl(pB.y, qid + 8));                             \
        float fB3 = __int_as_float(__shfl(pB.y, qid + 12));                            \
        uint2 vA0 = TAB[((unsigned)sA0 << 4) | ql];                                    \
        uint2 vA1 = TAB[((unsigned)sA1 << 4) | ql];                                    \
        uint2 vA2 = TAB[((unsigned)sA2 << 4) | ql];                                    \
        uint2 vA3 = TAB[((unsigned)sA3 << 4) | ql];                                    \
        uint2 vB0 = TAB[((unsigned)sB0 << 4) | ql];                                    \
        uint2 vB1 = TAB[((unsigned)sB1 << 4) | ql];                                    \
        uint2 vB2 = TAB[((unsigned)sB2 << 4) | ql];                                    \
        uint2 vB3 = TAB[((unsigned)sB3 << 4) | ql];                                    \
        vSA = TAB[((unsigned)nA << 4) | ql];                                           \
        vSB = TAB[((unsigned)nB << 4) | ql];                                           \
        a0 = fmaf(fA0, blo(vA0.x), a0); a1 = fmaf(fA0, bhi(vA0.x), a1);                \
        a2 = fmaf(fA0, blo(vA0.y), a2); a3 = fmaf(fA0, bhi(vA0.y), a3);                \
        a0 = fmaf(fA1, blo(vA1.x), a0); a1 = fmaf(fA1, bhi(vA1.x), a1);                \
        a2 = fmaf(fA1, blo(vA1.y), a2); a3 = fmaf(fA1, bhi(vA1.y), a3);                \
        a0 = fmaf(fA2, blo(vA2.x), a0); a1 = fmaf(fA2, bhi(vA2.x), a1);                \
        a2 = fmaf(fA2, blo(vA2.y), a2); a3 = fmaf(fA2, bhi(vA2.y), a3);                \
        a0 = fmaf(fA3, blo(vA3.x), a0); a1 = fmaf(fA3, bhi(vA3.x), a1);                \
        a2 = fmaf(fA3, blo(vA3.y), a2); a3 = fmaf(fA3, bhi(vA3.y), a3);                \
        b0 = fmaf(fB0, blo(vB0.x), b0); b1 = fmaf(fB0, bhi(vB0.x), b1);                \
        b2 = fmaf(fB0, blo(vB0.y), b2); b3 = fmaf(fB0, bhi(vB0.y), b3);                \
        b0 = fmaf(fB1, blo(vB1.x), b0); b1 = fmaf(fB1, bhi(vB1.x), b1);                \
        b2 = fmaf(fB1, blo(vB1.y), b2); b3 = fmaf(fB1, bhi(vB1.y), b3);                \
        b0 = fmaf(fB2, blo(vB2.x), b0); b1 = fmaf(fB2, bhi(vB2.x), b1);                \
        b2 = fmaf(fB2, blo(vB2.y), b2); b3 = fmaf(fB2, bhi(vB2.y), b3);                \
        b0 = fmaf(fB3, blo(vB3.x), b0); b1 = fmaf(fB3, bhi(vB3.x), b1);                \
        b2 = fmaf(fB3, blo(vB3.y), b2); b3 = fmaf(fB3, bhi(vB3.y), b3);                \
        int tsA = (cmA > 16) ? ((cmA - 13) >> 2) : 0;                                  \
        for (int k = 0; k < tsA; ++k) {                                                \
            int jj = 16 + 4 * k + qid;                                                 \
            int   s = __shfl(pA.x, jj);                                                \
            float f = __int_as_float(__shfl(pA.y, jj));                                \
            uint2 v = TAB[((unsigned)s << 4) | ql];                                    \
            a0 = fmaf(f, blo(v.x), a0); a1 = fmaf(f, bhi(v.x), a1);                    \
            a2 = fmaf(f, blo(v.y), a2); a3 = fmaf(f, bhi(v.y), a3);                    \
        }                                                                              \
        int tsB = (cmB > 16) ? ((cmB - 13) >> 2) : 0;                                  \
        for (int k = 0; k < tsB; ++k) {                                                \
            int jj = 16 + 4 * k + qid;                                                 \
            int   s = __shfl(pB.x, jj);                                                \
            float f = __int_as_float(__shfl(pB.y, jj));                                \
            uint2 v = TAB[((unsigned)s << 4) | ql];                                    \
            b0 = fmaf(f, blo(v.x), b0); b1 = fmaf(f, bhi(v.x), b1);                    \
            b2 = fmaf(f, blo(v.y), b2); b3 = fmaf(f, bhi(v.y), b3);                    \
        }                                                                              \
        a0 += __shfl_xor(a0, 16); a1 += __shfl_xor(a1, 16);                            \
        a2 += __shfl_xor(a2, 16); a3 += __shfl_xor(a3, 16);                            \
        a0 += __shfl_xor(a0, 32); a1 += __shfl_xor(a1, 32);                            \
        a2 += __shfl_xor(a2, 32); a3 += __shfl_xor(a3, 32);                            \
        b0 += __shfl_xor(b0, 16); b1 += __shfl_xor(b1, 16);                            \
        b2 += __shfl_xor(b2, 16); b3 += __shfl_xor(b3, 16);                            \
        b0 += __shfl_xor(b0, 32); b1 += __shfl_xor(b1, 32);                            \
        b2 += __shfl_xor(b2, 32); b3 += __shfl_xor(b3, 32);                            \
    }

// -------- fused layer 1+2-GEMM: t2u = bf16( dis * (relu((A_hat x)W1 + b1)) W2 ) ----
// bounds(256,4): empirically the only spill-free point for this kernel family
// (r6 bounds-6 / r9 bounds-8 both spilled).

__global__ __launch_bounds__(256, 4) void k_layer1(
        const uint2* __restrict__ xb2, const int2* __restrict__ csr,
        const int* __restrict__ rowptr, const int* __restrict__ counts,
        const float* __restrict__ dis, const unsigned short* __restrict__ wf1,
        const unsigned short* __restrict__ wf2, const float* __restrict__ b1,
        unsigned short* __restrict__ t2u) {
    __shared__ unsigned short sagg_b[32][72];     // bf16 agg tile, 144B rows
    __shared__ unsigned short sh1[32][136];       // bf16 h1 tile, 272B rows
    __shared__ float sb[H2X];
    int tid = threadIdx.x;
    if (tid < H2X) sb[tid] = b1[tid];

    int wave = tid >> 6, lane = tid & 63;
    int qid = lane >> 4, ql = lane & 15;
    int n0 = blockIdx.x * 32;
    int nb = n0 + wave * 8;

    int cm8[8], cnt8[8], rs8[8];
    float dn8[8];
    int2 myp[8];
    #pragma unroll
    for (int i = 0; i < 8; ++i) {
        rs8[i] = rowptr[nb + i];
        cnt8[i] = counts[nb + i];
        dn8[i] = dis[nb + i];
        cm8[i] = cnt8[i] < 64 ? cnt8[i] : 64;
    }
    #pragma unroll
    for (int i = 0; i < 8; ++i)
        myp[i] = (lane < cm8[i]) ? csr[rs8[i] + lane] : make_int2(0, 0);

    #pragma unroll
    for (int ip = 0; ip < 8; ip += 2) {
        int2 pA = myp[ip], pB = myp[ip + 1];
        int nA = nb + ip, nB = nA + 1;
        float a0 = 0.f, a1 = 0.f, a2 = 0.f, a3 = 0.f;
        float b0 = 0.f, b1v = 0.f, b2v = 0.f, b3 = 0.f;
        uint2 vSA, vSB;
        GATHER_PAIR(xb2, pA, pB, nA, nB, cm8[ip], cm8[ip + 1],
                    a0, a1, a2, a3, b0, b1v, b2v, b3, vSA, vSB);
        for (int jj = 64; jj < cnt8[ip]; ++jj) {   // degree >64: essentially never
            int2 p = csr[rs8[ip] + jj];
            float f = __int_as_float(p.y);
            uint2 v = xb2[((unsigned)p.x << 4) | ql];
            if (qid == 0) {
                a0 += f * blo(v.x); a1 += f * bhi(v.x);
                a2 += f * blo(v.y); a3 += f * bhi(v.y);
            }
        }
        for (int jj = 64; jj < cnt8[ip + 1]; ++jj) {
            int2 p = csr[rs8[ip + 1] + jj];
            float f = __int_as_float(p.y);
            uint2 v = xb2[((unsigned)p.x << 4) | ql];
            if (qid == 0) {
                b0 += f * blo(v.x); b1v += f * bhi(v.x);
                b2v += f * blo(v.y); b3 += f * bhi(v.y);
            }
        }
        if (qid == 0) {
            float dnA = dn8[ip], dnB = dn8[ip + 1];
            int m = wave * 8 + ip;
            *(uint2*)&sagg_b[m][ql * 4] =
                make_uint2(pack2(dnA * (a0 + blo(vSA.x)), dnA * (a1 + bhi(vSA.x))),
                           pack2(dnA * (a2 + blo(vSA.y)), dnA * (a3 + bhi(vSA.y))));
            *(uint2*)&sagg_b[m + 1][ql * 4] =
                make_uint2(pack2(dnB * (b0 + blo(vSB.x)), dnB * (b1v + bhi(vSB.x))),
                           pack2(dnB * (b2v + blo(vSB.y)), dnB * (b3 + bhi(vSB.y))));
        }
    }
    __syncthreads();

    // MFMA GEMM 1: agg(32x64) @ W1(64x128) -> relu+bias -> sh1 (bf16)
    int mt = wave & 1, ntb = (wave >> 1) * 4;
    int lm = lane & 15, lq = lane >> 4;
    bf16x8 af0 = *(const bf16x8*)&sagg_b[mt*16 + lm][lq * 8];
    bf16x8 af1 = *(const bf16x8*)&sagg_b[mt*16 + lm][32 + lq * 8];
    #pragma unroll
    for (int t = 0; t < 4; ++t) {
        int nt = ntb + t;
        bf16x8 bf0 = *(const bf16x8*)&wf1[(nt*64 + lane) * 8];
        bf16x8 bf1 = *(const bf16x8*)&wf1[((8 + nt)*64 + lane) * 8];
        f32x4 acc = {0.f, 0.f, 0.f, 0.f};
        acc = __builtin_amdgcn_mfma_f32_16x16x32_bf16(af0, bf0, acc, 0, 0, 0);
        acc = __builtin_amdgcn_mfma_f32_16x16x32_bf16(af1, bf1, acc, 0, 0, 0);
        int ch = nt*16 + lm;
        float bias = sb[ch];
        #pragma unroll
        for (int r = 0; r < 4; ++r)
            sh1[mt*16 + lq*4 + r][ch] = f2b(fmaxf(acc[r] + bias, 0.f));
    }
    __syncthreads();

    // MFMA GEMM 2: sh1(32x128) @ W2(128x64) -> t2u = bf16(dis * .)
    #pragma unroll
    for (int ti = 0; ti < 2; ++ti) {
        int t = wave * 2 + ti;                    // 8 tiles: 2 mt x 4 nt
        int mt2 = t & 1, nt2 = t >> 1;
        f32x4 acc = {0.f, 0.f, 0.f, 0.f};
        #pragma unroll
        for (int kt = 0; kt < 4; ++kt) {
            bf16x8 af = *(const bf16x8*)&sh1[mt2*16 + lm][kt*32 + lq*8];
            bf16x8 bf = *(const bf16x8*)&wf2[((kt*4 + nt2)*64 + lane) * 8];
            acc = __builtin_amdgcn_mfma_f32_16x16x32_bf16(af, bf, acc, 0, 0, 0);
        }
        int ch = nt2*16 + lm;
        #pragma unroll
        for (int r = 0; r < 4; ++r) {
            int node = n0 + mt2*16 + lq*4 + r;
            t2u[(size_t)node * HID + ch] = f2b(dis[node] * acc[r]);
        }
    }
}

// ---------------- layer 2 aggregation: h2b = bf16(relu( dn*(sum ew*t2y + t2y[n]) + b2 ))
// NOTE (r12 lesson): do NOT fuse load-dependent epilogues (e.g. FC Wfc loads)
// into this loop's tail — added load->use chains under quarter-lane divergence
// cost +23us. Stores are fine; loads are not.

__global__ __launch_bounds__(256, 4) void k_agg2(
        const uint2* __restrict__ t2y, const int2* __restrict__ csr,
        const int* __restrict__ rowptr, const int* __restrict__ counts,
        const float* __restrict__ dis, const float* __restrict__ b2,
        unsigned short* __restrict__ h2b) {
    int tid = threadIdx.x;
    int wave = tid >> 6, lane = tid & 63;
    int qid = lane >> 4, ql = lane & 15;
    float4 bb = *(const float4*)&b2[ql * 4];
    int n0 = blockIdx.x * 32;
    int nb = n0 + wave * 8;

    int cm8[8], cnt8[8], rs8[8];
    float dn8[8];
    int2 myp[8];
    #pragma unroll
    for (int i = 0; i < 8; ++i) {
        rs8[i] = rowptr[nb + i];
        cnt8[i] = counts[nb + i];
        dn8[i] = dis[nb + i];
        cm8[i] = cnt8[i] < 64 ? cnt8[i] : 64;
    }
    #pragma unroll
    for (int i = 0; i < 8; ++i)
        myp[i] = (lane < cm8[i]) ? csr[rs8[i] + lane] : make_int2(0, 0);

    #pragma unroll
    for (int ip = 0; ip < 8; ip += 2) {
        int2 pA = myp[ip], pB = myp[ip + 1];
        int nA = nb + ip, nB = nA + 1;
        float a0 = 0.f, a1 = 0.f, a2 = 0.f, a3 = 0.f;
        float b0 = 0.f, b1v = 0.f, b2v = 0.f, b3 = 0.f;
        uint2 vSA, vSB;
        GATHER_PAIR(t2y, pA, pB, nA, nB, cm8[ip], cm8[ip + 1],
                    a0, a1, a2, a3, b0, b1v, b2v, b3, vSA, vSB);
        for (int jj = 64; jj < cnt8[ip]; ++jj) {
            int2 p = csr[rs8[ip] + jj];
            float f = __int_as_float(p.y);
            uint2 v = t2y[((unsigned)p.x << 4) | ql];
            if (qid == 0) {
                a0 += f * blo(v.x); a1 += f * bhi(v.x);
                a2 += f * blo(v.y); a3 += f * bhi(v.y);
            }
        }
        for (int jj = 64; jj < cnt8[ip + 1]; ++jj) {
            int2 p = csr[rs8[ip + 1] + jj];
            float f = __int_as_float(p.y);
            uint2 v = t2y[((unsigned)p.x << 4) | ql];
            if (qid == 0) {
                b0 += f * blo(v.x); b1v += f * bhi(v.x);
                b2v += f * blo(v.y); b3 += f * bhi(v.y);
            }
        }
        if (qid == 0) {
            float dnA = dn8[ip], dnB = dn8[ip + 1];
            float oa0 = fmaxf(fmaf(dnA, a0 + blo(vSA.x), bb.x), 0.f);
            float oa1 = fmaxf(fmaf(dnA, a1 + bhi(vSA.x), bb.y), 0.f);
            float oa2 = fmaxf(fmaf(dnA, a2 + blo(vSA.y), bb.z), 0.f);
            float oa3 = fmaxf(fmaf(dnA, a3 + bhi(vSA.y), bb.w), 0.f);
            float ob0 = fmaxf(fmaf(dnB, b0 + blo(vSB.x), bb.x), 0.f);
            float ob1 = fmaxf(fmaf(dnB, b1v + bhi(vSB.x), bb.y), 0.f);
            float ob2 = fmaxf(fmaf(dnB, b2v + blo(vSB.y), bb.z), 0.f);
            float ob3 = fmaxf(fmaf(dnB, b3 + bhi(vSB.y), bb.w), 0.f);
            *(uint2*)&h2b[((unsigned)nA << 6) | (ql * 4)] =
                make_uint2(pack2(oa0, oa1), pack2(oa2, oa3));
            *(uint2*)&h2b[((unsigned)nB << 6) | (ql * 4)] =
                make_uint2(pack2(ob0, ob1), pack2(ob2, ob3));
        }
    }
}

// ---------------- FC + softmax (bf16 h2) ----------------

__global__ __launch_bounds__(256) void k_fc(
        const unsigned short* __restrict__ h2b, const float* __restrict__ Wfc,
        const float* __restrict__ bfc, float* __restrict__ out) {
    __shared__ float4 red[256];
    int b = blockIdx.x, t = threadIdx.x;
    const uint2* hrow = (const uint2*)(h2b + (size_t)b * (HID * NODESG));
    const float4* W4 = (const float4*)Wfc;
    float4 a = make_float4(0.f, 0.f, 0.f, 0.f);
    #pragma unroll
    for (int j = 0; j < 8; ++j) {
        int i = j * 256 + t;                    // uint2 index: 4 channels
        uint2 hv = hrow[i];
        float h0 = blo(hv.x), h1 = bhi(hv.x), h2v = blo(hv.y), h3 = bhi(hv.y);
        float4 w0 = W4[i * 4 + 0];
        float4 w1 = W4[i * 4 + 1];
        float4 w2 = W4[i * 4 + 2];
        float4 w3 = W4[i * 4 + 3];
        a.x = fmaf(h0, w0.x, a.x); a.y = fmaf(h0, w0.y, a.y);
        a.z = fmaf(h0, w0.z, a.z); a.w = fmaf(h0, w0.w, a.w);
        a.x = fmaf(h1, w1.x, a.x); a.y = fmaf(h1, w1.y, a.y);
        a.z = fmaf(h1, w1.z, a.z); a.w = fmaf(h1, w1.w, a.w);
        a.x = fmaf(h2v, w2.x, a.x); a.y = fmaf(h2v, w2.y, a.y);
        a.z = fmaf(h2v, w2.z, a.z); a.w = fmaf(h2v, w2.w, a.w);
        a.x = fmaf(h3, w3.x, a.x); a.y = fmaf(h3, w3.y, a.y);
        a.z = fmaf(h3, w3.z, a.z); a.w = fmaf(h3, w3.w, a.w);
    }
    red[t] = a;
    __syncthreads();
    for (int s = 128; s > 0; s >>= 1) {
        if (t < s) {
            red[t].x += red[t + s].x; red[t].y += red[t + s].y;
            red[t].z += red[t + s].z; red[t].w += red[t + s].w;
        }
        __syncthreads();
    }
    if (t == 0) {
        float l0 = red[0].x + bfc[0];
        float l1 = red[0].y + bfc[1];
        float l2 = red[0].z + bfc[2];
        float l3 = red[0].w + bfc[3];
        float mx = fmaxf(fmaxf(l0, l1), fmaxf(l2, l3));
        float e0 = expf(l0 - mx), e1 = expf(l1 - mx);
        float e2 = expf(l2 - mx), e3 = expf(l3 - mx);
        float inv = 1.f / (e0 + e1 + e2 + e3);
        float4 o = make_float4(e0 * inv, e1 * inv, e2 * inv, e3 * inv);
        *(float4*)&out[(size_t)b * 4] = o;
    }
}

// ---------------- launch ----------------

extern "C" void kernel_launch(void* const* d_in, const int* in_sizes, int n_in,
                              void* d_out, int out_size, void* d_ws, size_t ws_size,
                              hipStream_t stream) {
    const float* x   = (const float*)d_in[0];
    const int*   ei  = (const int*)  d_in[1];
    const float* ea  = (const float*)d_in[2];
    const float* W1  = (const float*)d_in[3];
    const float* b1  = (const float*)d_in[4];
    const float* W2  = (const float*)d_in[5];
    const float* b2  = (const float*)d_in[6];
    const float* Wfc = (const float*)d_in[7];
    const float* bfc = (const float*)d_in[8];
    float* out = (float*)d_out;
    const int* src = ei;
    const int* dst = ei + NE;

    char* ws = (char*)d_ws;
    size_t off = 0;
    int*   hist   = (int*)  (ws + off); off += (size_t)NBUCK * HBLK * 4;  // 1 MB
    int*   partial= (int*)  (ws + off); off += 4096;
    int*   counts = (int*)  (ws + off); off += (size_t)N_NODES * 4;
    int*   rowptr = (int*)  (ws + off); off += (size_t)N_NODES * 4;
    float* dis    = (float*)(ws + off); off += (size_t)N_NODES * 4;
    unsigned short* wf1 = (unsigned short*)(ws + off); off += 8192 * 2;   // 16 KB
    unsigned short* wf2 = (unsigned short*)(ws + off); off += 8192 * 2;   // 16 KB
    int2*  csr    = (int2*) (ws + off); off += (size_t)NE * 8;
    uint2* xb2    = (uint2*)(ws + off); off += (size_t)N_NODES * CIN * 2;
    unsigned short* t2u = (unsigned short*)(ws + off); off += (size_t)N_NODES * HID * 2;
    unsigned short* h2b = (unsigned short*)(ws + off); off += (size_t)N_NODES * HID * 2;
    unsigned long long* part = (unsigned long long*)t2u; // 16MB <= 16.7MB; dead before k_layer1

    // zero hist + partial (contiguous)
    hipMemsetAsync(hist, 0, (size_t)NBUCK * HBLK * 4 + 4096, stream);

    k_wswiz  <<<1, 256, 0, stream>>>(W1, W2, wf1, wf2);
    k_hist   <<<HBLK, 256, 0, stream>>>(dst, hist);
    k_scan1  <<<NBUCK * HBLK / 512, 256, 0, stream>>>(hist, hist, partial);
    k_scan2  <<<1, 256, 0, stream>>>(partial);
    k_scatter<<<HBLK, 256, 0, stream>>>(src, dst, ea, hist, partial, part);
    k_bucket <<<NBUCK, 256, 0, stream>>>(part, hist, partial, csr, rowptr, counts, dis);
    k_xcast  <<<(N_NODES * CIN / 4) / 256, 256, 0, stream>>>(x, dis, xb2);
    k_layer1 <<<N_NODES / 32, 256, 0, stream>>>(xb2, csr, rowptr, counts, dis,
                                                wf1, wf2, b1, t2u);
    k_agg2   <<<N_NODES / 32, 256, 0, stream>>>((const uint2*)t2u, csr, rowptr,
                                                counts, dis, b2, h2b);
    k_fc     <<<NGRAPH, 256, 0, stream>>>(h2b, Wfc, bfc, out);
}